// Round 10
// baseline (7340.054 us; speedup 1.0000x reference)
//
#include <hip/hip_runtime.h>
#include <hip/hip_bf16.h>

#define B_ 256
#define S_ 2048
#define D_ 16
#define H_ 128

typedef unsigned int u32;
typedef unsigned short u16;
typedef _Float16 h2t __attribute__((ext_vector_type(2)));
typedef _Float16 f16x8 __attribute__((ext_vector_type(8)));
typedef float f32x4 __attribute__((ext_vector_type(4)));

// ---- output layout (flat f32): returns | volatility | hidden_h | hidden_c
#define RET0 ((size_t)0)
#define VOL0 ((size_t)524288)
#define HH0  ((size_t)1048576)
#define HC0  ((size_t)1114112)

#define MFMA16(a, b, c) __builtin_amdgcn_mfma_f32_16x16x32_f16(a, b, c, 0, 0, 0)

__device__ __forceinline__ u32 packh2(float a, float b) {
    h2t h; h[0] = (_Float16)a; h[1] = (_Float16)b;
    return __builtin_bit_cast(u32, h);
}
__device__ __forceinline__ f16x8 pk8(float4 a, float4 b) {
    f16x8 r;
    r[0] = (_Float16)a.x; r[1] = (_Float16)a.y; r[2] = (_Float16)a.z; r[3] = (_Float16)a.w;
    r[4] = (_Float16)b.x; r[5] = (_Float16)b.y; r[6] = (_Float16)b.z; r[7] = (_Float16)b.w;
    return r;
}
__device__ __forceinline__ float sigm(float x) {
    return __builtin_amdgcn_rcpf(1.f + __builtin_amdgcn_exp2f(-1.44269504f * x));
}
__device__ __forceinline__ float tanh_(float x) {
    return 2.f * __builtin_amdgcn_rcpf(1.f + __builtin_amdgcn_exp2f(-2.88539008f * x)) - 1.f;
}
__device__ __forceinline__ float softplus_(float x) {
    if (x > 20.f) return x;
    const float e = __builtin_amdgcn_exp2f(1.44269504f * x);
    return 0.69314718f * __builtin_amdgcn_logf(1.f + e);
}
__device__ __forceinline__ float4 ld4(const float* p) { return *(const float4*)p; }

// ring: [slot 8][row 16][64 u32], 16B chunks XOR-swizzled by (row&7)
// ws h-layout: [group 16][t 2048][row 16][64 u32 pairs]  (h1, overwritten by h2)

// ===================== layer 0 (MFMA, 16 rows/block) ========================
__global__ __launch_bounds__(512, 2) void k_l0m(
    const float* __restrict__ x, const float* __restrict__ Wih,
    const float* __restrict__ Whh, const float* __restrict__ bih,
    const float* __restrict__ bhh, u32* __restrict__ hws,
    float* __restrict__ out)
{
    __shared__ u32 ring[8192];   // 32KB h1 ring (8 steps)

    const int tid = threadIdx.x, g = blockIdx.x;
    const int l = tid & 63, w = tid >> 6;
    const int ub = w * 16;                 // unit base of this wave
    const int col = l & 15, kg = l >> 4;   // frag col / k-group

    f16x8 wB[4][5];
    float bias[4];
#pragma unroll
    for (int gt = 0; gt < 4; ++gt) {
        const int n = gt * 128 + ub + col;
        if (kg < 2) {       // x K-tile: k = kg*8.. (<16 valid)
            const float* p = Wih + n * 16 + kg * 8;
            wB[gt][0] = pk8(ld4(p), ld4(p + 4));
        } else {
            f16x8 z = {0, 0, 0, 0, 0, 0, 0, 0};
            wB[gt][0] = z;
        }
#pragma unroll
        for (int kt = 1; kt < 5; ++kt) {
            const float* p = Whh + n * 128 + (kt - 1) * 32 + kg * 8;
            wB[gt][kt] = pk8(ld4(p), ld4(p + 4));
        }
        bias[gt] = bih[n] + bhh[n];
    }

    for (int i = tid; i < 8192; i += 512) ring[i] = 0;
    float c1[4] = {0.f, 0.f, 0.f, 0.f};
    __syncthreads();

    const float* xrow = x + ((size_t)(g * 16 + col) * S_) * D_;
    for (int t = 0; t < S_; ++t) {
        // A-frag: x (direct from global, L1-served; lanes kg>=2 are zero-pad)
        f16x8 ax = {0, 0, 0, 0, 0, 0, 0, 0};
        if (kg < 2) {
            const float* xp = xrow + t * 16 + kg * 8;
            ax = pk8(ld4(xp), ld4(xp + 4));
        }
        // A-frags: h1_{t-1} from ring
        f16x8 ah[4];
        {
            const int sl = ((t - 1) & 7) << 10;
#pragma unroll
            for (int kt = 0; kt < 4; ++kt)
                ah[kt] = __builtin_bit_cast(f16x8,
                    *(const uint4*)&ring[sl + col * 64 + (((kt * 4 + kg) ^ (col & 7)) << 2)]);
        }
        // MFMA: 4 gate-tiles x 5 K-tiles
        f32x4 acc[4];
#pragma unroll
        for (int gt = 0; gt < 4; ++gt) {
            f32x4 a = {bias[gt], bias[gt], bias[gt], bias[gt]};
            a = MFMA16(ax, wB[gt][0], a);
#pragma unroll
            for (int kt = 1; kt < 5; ++kt) a = MFMA16(ah[kt - 1], wB[gt][kt], a);
            acc[gt] = a;
        }
        // cell update: lane-local (row = kg*4+j, unit = ub+col)
#pragma unroll
        for (int j = 0; j < 4; ++j) {
            const float ai = acc[0][j], af = acc[1][j], ag = acc[2][j], ao = acc[3][j];
            c1[j] = sigm(af) * c1[j] + sigm(ai) * tanh_(ag);
            const float h = sigm(ao) * tanh_(c1[j]);
            const u32 hp = packh2(h, __shfl_down(h, 1));
            const int r = kg * 4 + j;
            if (!(l & 1)) {
                const int p = (ub + col) >> 1;
                ring[((t & 7) << 10) + r * 64 + ((((p >> 2)) ^ (r & 7)) << 2) + (p & 3)] = hp;
            }
            if (t == S_ - 1) {
                const size_t b = g * 16 + r;
                out[HH0 + b * H_ + ub + col] = h;
                out[HC0 + b * H_ + ub + col] = c1[j];
            }
        }
        __syncthreads();
        if ((t & 7) == 7) {      // flush 8 steps to ws (de-swizzled, coalesced)
#pragma unroll
            for (int q = 0; q < 4; ++q) {
                const int ch = tid * 4 + q;
                const int s = ch >> 8, rr = (ch >> 4) & 15, cc = ch & 15;
                const uint4 v = *(const uint4*)&ring[(s << 10) + rr * 64 + ((cc ^ (rr & 7)) << 2)];
                *(uint4*)(hws + (((size_t)g * S_ + (t - 7 + s)) * 16 + rr) * 64 + cc * 4) = v;
            }
            __syncthreads();
        }
    }
}

// ===================== layer 1 (MFMA), h2 overwrites h1 in ws ===============
__global__ __launch_bounds__(512, 2) void k_l1m(
    u32* __restrict__ hws,
    const float* __restrict__ Wih, const float* __restrict__ Whh,
    const float* __restrict__ bih, const float* __restrict__ bhh,
    float* __restrict__ out)
{
    __shared__ u32 ring[8192];   // 32KB h2 ring

    const int tid = threadIdx.x, g = blockIdx.x;
    const int l = tid & 63, w = tid >> 6;
    const int ub = w * 16;
    const int col = l & 15, kg = l >> 4;

    f16x8 wB[4][8];
    float bias[4];
#pragma unroll
    for (int gt = 0; gt < 4; ++gt) {
        const int n = gt * 128 + ub + col;
#pragma unroll
        for (int kt = 0; kt < 8; ++kt) {
            const float* p = ((kt < 4) ? Wih : Whh) + n * 128 + (kt & 3) * 32 + kg * 8;
            wB[gt][kt] = pk8(ld4(p), ld4(p + 4));
        }
        bias[gt] = bih[n] + bhh[n];
    }

    for (int i = tid; i < 8192; i += 512) ring[i] = 0;
    float c2[4] = {0.f, 0.f, 0.f, 0.f};
    __syncthreads();

    for (int u = 0; u < S_; ++u) {
        // A-frags: h1_u from global ws (L3-resident)
        f16x8 a1[4];
        {
            const u32* hrow = hws + (((size_t)g * S_ + u) * 16 + col) * 64;
#pragma unroll
            for (int kt = 0; kt < 4; ++kt)
                a1[kt] = __builtin_bit_cast(f16x8, *(const uint4*)(hrow + kt * 16 + kg * 4));
        }
        // A-frags: h2_{u-1} from ring
        f16x8 a2[4];
        {
            const int sl = ((u - 1) & 7) << 10;
#pragma unroll
            for (int kt = 0; kt < 4; ++kt)
                a2[kt] = __builtin_bit_cast(f16x8,
                    *(const uint4*)&ring[sl + col * 64 + (((kt * 4 + kg) ^ (col & 7)) << 2)]);
        }
        f32x4 acc[4];
#pragma unroll
        for (int gt = 0; gt < 4; ++gt) {
            f32x4 a = {bias[gt], bias[gt], bias[gt], bias[gt]};
#pragma unroll
            for (int kt = 0; kt < 4; ++kt) a = MFMA16(a1[kt], wB[gt][kt], a);
#pragma unroll
            for (int kt = 4; kt < 8; ++kt) a = MFMA16(a2[kt - 4], wB[gt][kt], a);
            acc[gt] = a;
        }
#pragma unroll
        for (int j = 0; j < 4; ++j) {
            const float ai = acc[0][j], af = acc[1][j], ag = acc[2][j], ao = acc[3][j];
            c2[j] = sigm(af) * c2[j] + sigm(ai) * tanh_(ag);
            const float h = sigm(ao) * tanh_(c2[j]);
            const u32 hp = packh2(h, __shfl_down(h, 1));
            const int r = kg * 4 + j;
            if (!(l & 1)) {
                const int p = (ub + col) >> 1;
                ring[((u & 7) << 10) + r * 64 + ((((p >> 2)) ^ (r & 7)) << 2) + (p & 3)] = hp;
            }
            if (u == S_ - 1) {
                const size_t b = g * 16 + r;
                out[HH0 + 32768 + b * H_ + ub + col] = h;
                out[HC0 + 32768 + b * H_ + ub + col] = c2[j];
            }
        }
        __syncthreads();
        if ((u & 7) == 7) {      // flush h2, in-place over consumed h1
#pragma unroll
            for (int q = 0; q < 4; ++q) {
                const int ch = tid * 4 + q;
                const int s = ch >> 8, rr = (ch >> 4) & 15, cc = ch & 15;
                const uint4 v = *(const uint4*)&ring[(s << 10) + rr * 64 + ((cc ^ (rr & 7)) << 2)];
                *(uint4*)(hws + (((size_t)g * S_ + (u - 7 + s)) * 16 + rr) * 64 + cc * 4) = v;
            }
            __syncthreads();
        }
    }
}

// ===================== heads: parallel over (b,s) ===========================
__global__ __launch_bounds__(256) void k_heads(
    const u32* __restrict__ h2p,
    const float* __restrict__ Wr1, const float* __restrict__ br1,
    const float* __restrict__ Wr2, const float* __restrict__ br2,
    const float* __restrict__ Wv1, const float* __restrict__ bv1,
    const float* __restrict__ Wv2, const float* __restrict__ bv2,
    float* __restrict__ out)
{
    __shared__ u32 wr[64 * 64], wv[64 * 64];
    __shared__ float w2r[64], w2v[64], b1r[64], b1v[64];

    const int tid = threadIdx.x;
    for (int i = tid; i < 4096; i += 256) {
        wr[i] = packh2(Wr1[2 * i], Wr1[2 * i + 1]);
        wv[i] = packh2(Wv1[2 * i], Wv1[2 * i + 1]);
    }
    if (tid < 64) {
        w2r[tid] = Wr2[tid]; w2v[tid] = Wv2[tid];
        b1r[tid] = br1[tid]; b1v[tid] = bv1[tid];
    }
    __syncthreads();

    const int g = blockIdx.x >> 7;                // 16 groups
    const int s = (blockIdx.x & 127) * 16 + (tid >> 4);
    const int r = tid & 15;
    const int b = g * 16 + r;

    u32 hq[64];
    const u32* src = h2p + (((size_t)g * S_ + s) * 16 + r) * 64;
#pragma unroll
    for (int j4 = 0; j4 < 16; ++j4) {
        const uint4 v = *(const uint4*)(src + j4 * 4);
        hq[j4 * 4] = v.x; hq[j4 * 4 + 1] = v.y; hq[j4 * 4 + 2] = v.z; hq[j4 * 4 + 3] = v.w;
    }
    float ret = br2[0], vol = bv2[0];
    for (int k = 0; k < 64; ++k) {
        float rr = b1r[k], vv = b1v[k];
#pragma unroll
        for (int j = 0; j < 64; ++j) {
            rr = __builtin_amdgcn_fdot2(__builtin_bit_cast(h2t, hq[j]),
                                        __builtin_bit_cast(h2t, wr[k * 64 + j]), rr, false);
            vv = __builtin_amdgcn_fdot2(__builtin_bit_cast(h2t, hq[j]),
                                        __builtin_bit_cast(h2t, wv[k * 64 + j]), vv, false);
        }
        rr = rr > 0.f ? rr : 0.01f * rr;
        vv = vv > 0.f ? vv : 0.01f * vv;
        ret += rr * w2r[k];
        vol += vv * w2v[k];
    }
    out[RET0 + (size_t)b * S_ + s] = ret;
    out[VOL0 + (size_t)b * S_ + s] = softplus_(vol);
}

extern "C" void kernel_launch(void* const* d_in, const int* in_sizes, int n_in,
                              void* d_out, int out_size, void* d_ws, size_t ws_size,
                              hipStream_t stream) {
    (void)in_sizes; (void)n_in; (void)out_size; (void)ws_size;
    const float* x    = (const float*)d_in[0];
    const float* Wih0 = (const float*)d_in[1];
    const float* Whh0 = (const float*)d_in[2];
    const float* bih0 = (const float*)d_in[3];
    const float* bhh0 = (const float*)d_in[4];
    const float* Wih1 = (const float*)d_in[5];
    const float* Whh1 = (const float*)d_in[6];
    const float* bih1 = (const float*)d_in[7];
    const float* bhh1 = (const float*)d_in[8];
    const float* Wr1  = (const float*)d_in[9];
    const float* br1  = (const float*)d_in[10];
    const float* Wr2  = (const float*)d_in[11];
    const float* br2  = (const float*)d_in[12];
    const float* Wv1  = (const float*)d_in[13];
    const float* bv1  = (const float*)d_in[14];
    const float* Wv2  = (const float*)d_in[15];
    const float* bv2  = (const float*)d_in[16];
    u32* hws  = (u32*)d_ws;    // 128 MiB: [16][2048][16][64] h1 pairs, then h2 in-place
    float* out = (float*)d_out;

    k_l0m<<<16, 512, 0, stream>>>(x, Wih0, Whh0, bih0, bhh0, hws, out);
    k_l1m<<<16, 512, 0, stream>>>(hws, Wih1, Whh1, bih1, bhh1, out);
    k_heads<<<2048, 256, 0, stream>>>(hws, Wr1, br1, Wr2, br2,
                                      Wv1, bv1, Wv2, bv2, out);
}

// Round 11
// 4013.109 us; speedup vs baseline: 1.8290x; 1.8290x over previous
//
#include <hip/hip_runtime.h>
#include <hip/hip_bf16.h>

#define B_ 256
#define S_ 2048
#define D_ 16
#define H_ 128

typedef unsigned int u32;
typedef unsigned short u16;
typedef _Float16 h2t __attribute__((ext_vector_type(2)));

// ---- output layout (flat f32): returns | volatility | hidden_h | hidden_c
#define RET0 ((size_t)0)
#define VOL0 ((size_t)524288)
#define HH0  ((size_t)1048576)
#define HC0  ((size_t)1114112)

// ---- ws layout (u32 units): [0, 33554432) h pairs [b*S+t][64] (h1, then h2
// in-place);  [33554432, 167772160) G1 [b*S+t][128 m][2] f16 gate pre-acts.
#define G1OFF ((size_t)33554432)
#define WS_NEED 671088640ull

__device__ __forceinline__ float fdot2(u32 a, u32 b, float c) {
    return __builtin_amdgcn_fdot2(__builtin_bit_cast(h2t, a),
                                  __builtin_bit_cast(h2t, b), c, false);
}
__device__ __forceinline__ u32 packh2(float a, float b) {
    h2t h; h[0] = (_Float16)a; h[1] = (_Float16)b;
    return __builtin_bit_cast(u32, h);
}
__device__ __forceinline__ float sigm(float x) {
    return __builtin_amdgcn_rcpf(1.f + __builtin_amdgcn_exp2f(-1.44269504f * x));
}
__device__ __forceinline__ float tanh_(float x) {
    return 2.f * __builtin_amdgcn_rcpf(1.f + __builtin_amdgcn_exp2f(-2.88539008f * x)) - 1.f;
}
__device__ __forceinline__ float softplus_(float x) {
    if (x > 20.f) return x;
    const float e = __builtin_amdgcn_exp2f(1.44269504f * x);
    return 0.69314718f * __builtin_amdgcn_logf(1.f + e);
}
// all-VALU 8-lane reduction: quad_perm xor1, xor2, then row_half_mirror (0x141)
__device__ __forceinline__ float dxor1(float a) {
    return __builtin_bit_cast(float, __builtin_amdgcn_update_dpp(
        0, __builtin_bit_cast(int, a), 0xB1, 0xF, 0xF, true));
}
__device__ __forceinline__ float dxor2(float a) {
    return __builtin_bit_cast(float, __builtin_amdgcn_update_dpp(
        0, __builtin_bit_cast(int, a), 0x4E, 0xF, 0xF, true));
}
__device__ __forceinline__ float dhalf(float a) {
    return __builtin_bit_cast(float, __builtin_amdgcn_update_dpp(
        0, __builtin_bit_cast(int, a), 0x141, 0xF, 0xF, true));
}
__device__ __forceinline__ float dror8(float a) {   // lane^8 within 16-lane row
    return __builtin_bit_cast(float, __builtin_amdgcn_update_dpp(
        0, __builtin_bit_cast(int, a), 0x128, 0xF, 0xF, true));
}
#define REDUCE8D(a) { a += dxor1(a); a += dxor2(a); a += dhalf(a); }

// ===================== layer 0 (serial; round-8 + DPP reduce) ===============
// 1024 thr: tid = m*8 + ksl. Thread: all 4 gates of unit m over K-eighth ksl.
__global__ __launch_bounds__(1024, 1) void k_l0(
    const float* __restrict__ x, const float* __restrict__ Wih,
    const float* __restrict__ Whh, const float* __restrict__ bih,
    const float* __restrict__ bhh, u32* __restrict__ h1out,
    float* __restrict__ out)
{
    __shared__ u32 xp2[2][4096];   // 512-step x window, f16 pairs (32KB)
    __shared__ u32 hb[2][64];      // h1 state double buffer (f16 pairs)
    __shared__ u32 och[4096];      // 64-step h1 output staging (16KB)

    const int tid = threadIdx.x, b = blockIdx.x;
    const int m = tid >> 3, ksl = tid & 7;

    u32 wx[4], wh[32];
    float bias[4];
#pragma unroll
    for (int g = 0; g < 4; ++g) {
        const int row = g * H_ + m;
        const float2 f2 = *(const float2*)(Wih + row * D_ + ksl * 2);
        wx[g] = packh2(f2.x, f2.y);
        const float4* whr = (const float4*)(Whh + row * H_ + ksl * 16);
#pragma unroll
        for (int j = 0; j < 4; ++j) {
            const float4 f = whr[j];
            wh[g * 8 + 2 * j]     = packh2(f.x, f.y);
            wh[g * 8 + 2 * j + 1] = packh2(f.z, f.w);
        }
        bias[g] = bih[row] + bhh[row];
    }

    const float* xb = x + (size_t)b * S_ * D_;
    for (int i = tid; i < 2048; i += 1024) {
        const float4 v = *(const float4*)(xb + i * 4);
        xp2[0][2 * i] = packh2(v.x, v.y);
        xp2[0][2 * i + 1] = packh2(v.z, v.w);
    }
    if (tid < 128) ((u32*)hb)[tid] = 0u;
    float c = 0.f;
    __syncthreads();

    for (int t = 0; t < S_; ++t) {
        if ((t & 511) == 0 && t < S_ - 512) {
            const int nw = (t >> 9) + 1;
            u32* dst = xp2[nw & 1];
            const float* src = xb + (size_t)nw * 8192;
            for (int i = tid; i < 2048; i += 1024) {
                const float4 v = *(const float4*)(src + i * 4);
                dst[2 * i] = packh2(v.x, v.y);
                dst[2 * i + 1] = packh2(v.z, v.w);
            }
        }
        const u32 xv = xp2[(t >> 9) & 1][(t & 511) * 8 + ksl];
        const u32* hsel = &hb[(t + 1) & 1][ksl * 8];
        const uint4 h0 = *(const uint4*)(hsel);
        const uint4 h1v = *(const uint4*)(hsel + 4);

        float a0 = fdot2(xv, wx[0], 0.f), a1 = fdot2(xv, wx[1], 0.f);
        float a2 = fdot2(xv, wx[2], 0.f), a3 = fdot2(xv, wx[3], 0.f);
#define L0G(comp, j)                                                           \
        a0 = fdot2(comp, wh[j], a0);        a1 = fdot2(comp, wh[8 + (j)], a1); \
        a2 = fdot2(comp, wh[16 + (j)], a2); a3 = fdot2(comp, wh[24 + (j)], a3);
        L0G(h0.x, 0) L0G(h0.y, 1) L0G(h0.z, 2) L0G(h0.w, 3)
        L0G(h1v.x, 4) L0G(h1v.y, 5) L0G(h1v.z, 6) L0G(h1v.w, 7)
#undef L0G
        REDUCE8D(a0) REDUCE8D(a1) REDUCE8D(a2) REDUCE8D(a3)
        const float ig = sigm(a0 + bias[0]);
        const float fg = sigm(a1 + bias[1]);
        const float gc = tanh_(a2 + bias[2]);
        const float og = sigm(a3 + bias[3]);
        c = fg * c + ig * gc;
        const float hv = og * tanh_(c);
        const u32 pp = packh2(hv, dror8(hv));
        if ((tid & 15) == 0) {                   // ksl==0 && m even
            hb[t & 1][m >> 1] = pp;
            och[(t & 63) * 64 + (m >> 1)] = pp;
        }
        if (t == S_ - 1 && (tid & 7) == 0) {
            out[HH0 + (size_t)b * H_ + m] = hv;
            out[HC0 + (size_t)b * H_ + m] = c;
        }
        __syncthreads();
        if ((t & 63) == 63) {                    // flush 64 h1 rows
            u32* dst = h1out + ((size_t)b * S_ + (t - 63)) * 64;
            *(uint4*)(dst + tid * 4) = *(const uint4*)(&och[tid * 4]);
            __syncthreads();
        }
    }
}

// ===================== G1 = bias + W_ih1 . h1  (parallel, per batch row) ====
__global__ __launch_bounds__(1024, 1) void k_g1(
    const u32* __restrict__ h1p, const float* __restrict__ Wih,
    const float* __restrict__ bih, const float* __restrict__ bhh,
    u32* __restrict__ g1)
{
    const int tid = threadIdx.x, b = blockIdx.x;
    const int m = tid >> 3, ksl = tid & 7;

    u32 w[32];
    float bias[4];
#pragma unroll
    for (int g = 0; g < 4; ++g) {
        const int row = g * H_ + m;
        const float4* wr_ = (const float4*)(Wih + row * H_ + ksl * 16);
#pragma unroll
        for (int j = 0; j < 4; ++j) {
            const float4 f = wr_[j];
            w[g * 8 + 2 * j]     = packh2(f.x, f.y);
            w[g * 8 + 2 * j + 1] = packh2(f.z, f.w);
        }
        bias[g] = bih[row] + bhh[row];
    }

    for (int t = 0; t < S_; ++t) {
        const u32* hp_ = h1p + ((size_t)b * S_ + t) * 64 + ksl * 8;
        const uint4 v0 = *(const uint4*)hp_;
        const uint4 v1 = *(const uint4*)(hp_ + 4);
        float a0 = 0.f, a1 = 0.f, a2 = 0.f, a3 = 0.f;
#define G1G(comp, j)                                                           \
        a0 = fdot2(comp, w[j], a0);        a1 = fdot2(comp, w[8 + (j)], a1);   \
        a2 = fdot2(comp, w[16 + (j)], a2); a3 = fdot2(comp, w[24 + (j)], a3);
        G1G(v0.x, 0) G1G(v0.y, 1) G1G(v0.z, 2) G1G(v0.w, 3)
        G1G(v1.x, 4) G1G(v1.y, 5) G1G(v1.z, 6) G1G(v1.w, 7)
#undef G1G
        REDUCE8D(a0) REDUCE8D(a1) REDUCE8D(a2) REDUCE8D(a3)
        if (ksl == 0) {
            uint2 o;
            o.x = packh2(a0 + bias[0], a1 + bias[1]);
            o.y = packh2(a2 + bias[2], a3 + bias[3]);
            *(uint2*)(g1 + (((size_t)b * S_ + t) * 128 + m) * 2) = o;
        }
    }
}

// ===================== layer 1 recurrence only (serial) =====================
// Gate pre-acts = G1 (streamed via LDS dbuf, register-prefetched) + Whh.h2.
__global__ __launch_bounds__(1024, 1) void k_l1r(
    u32* __restrict__ hws, const u32* __restrict__ g1,
    const float* __restrict__ Whh, float* __restrict__ out)
{
    __shared__ u32 gbuf[2][8192];  // 2 x 32-step G1 chunk (64KB)
    __shared__ u32 hp[2][80];      // h2 state dbuf, padded chunks of 20
    __shared__ u32 och[4096];      // 64-step h2 staging (16KB)

    const int tid = threadIdx.x, b = blockIdx.x;
    const int m = tid >> 3, ksl = tid & 7;

    u32 w[32];
#pragma unroll
    for (int g = 0; g < 4; ++g) {
        const int row = g * H_ + m;
        const float4* wr_ = (const float4*)(Whh + row * H_ + ksl * 16);
#pragma unroll
        for (int j = 0; j < 4; ++j) {
            const float4 f = wr_[j];
            w[g * 8 + 2 * j]     = packh2(f.x, f.y);
            w[g * 8 + 2 * j + 1] = packh2(f.z, f.w);
        }
    }

    if (tid < 160) ((u32*)hp)[tid] = 0u;
    const u32* gsrc = g1 + (size_t)b * S_ * 256;
    uint4 r0 = *(const uint4*)(gsrc + tid * 8);        // prefetch chunk 0
    uint4 r1 = *(const uint4*)(gsrc + tid * 8 + 4);
    float c = 0.f;
    __syncthreads();

    u32* hbase = hws + (size_t)b * S_ * 64;
    for (int u = 0; u < S_; ++u) {
        if ((u & 31) == 0) {                 // commit chunk, prefetch next
            const int cb = (u >> 5) & 1;
            *(uint4*)(&gbuf[cb][tid * 8]) = r0;
            *(uint4*)(&gbuf[cb][tid * 8 + 4]) = r1;
            __syncthreads();
            if (u + 32 < S_) {
                r0 = *(const uint4*)(gsrc + (size_t)(u + 32) * 256 + tid * 8);
                r1 = *(const uint4*)(gsrc + (size_t)(u + 32) * 256 + tid * 8 + 4);
            }
        }
        const u32* sel = &hp[(u + 1) & 1][(ksl >> 1) * 20 + (ksl & 1) * 8];
        const uint4 v0 = *(const uint4*)sel;
        const uint4 v1 = *(const uint4*)(sel + 4);
        float a0 = 0.f, a1 = 0.f, a2 = 0.f, a3 = 0.f;
#define L1G(comp, j)                                                           \
        a0 = fdot2(comp, w[j], a0);        a1 = fdot2(comp, w[8 + (j)], a1);   \
        a2 = fdot2(comp, w[16 + (j)], a2); a3 = fdot2(comp, w[24 + (j)], a3);
        L1G(v0.x, 0) L1G(v0.y, 1) L1G(v0.z, 2) L1G(v0.w, 3)
        L1G(v1.x, 4) L1G(v1.y, 5) L1G(v1.z, 6) L1G(v1.w, 7)
#undef L1G
        REDUCE8D(a0) REDUCE8D(a1) REDUCE8D(a2) REDUCE8D(a3)
        const uint2 gg = *(const uint2*)(&gbuf[(u >> 5) & 1][(u & 31) * 256 + m * 2]);
        const h2t plo = __builtin_bit_cast(h2t, gg.x);
        const h2t phi = __builtin_bit_cast(h2t, gg.y);
        const float ig = sigm(a0 + (float)plo[0]);
        const float fg = sigm(a1 + (float)plo[1]);
        const float gc = tanh_(a2 + (float)phi[0]);
        const float og = sigm(a3 + (float)phi[1]);
        c = fg * c + ig * gc;
        const float hv = og * tanh_(c);
        const u32 pp = packh2(hv, dror8(hv));
        if ((tid & 15) == 0) {
            const int m2 = m >> 1;
            hp[u & 1][(m2 >> 4) * 20 + (m2 & 15)] = pp;
            och[(u & 63) * 64 + m2] = pp;
        }
        if (u == S_ - 1 && (tid & 7) == 0) {
            out[HH0 + 32768 + (size_t)b * H_ + m] = hv;
            out[HC0 + 32768 + (size_t)b * H_ + m] = c;
        }
        __syncthreads();
        if ((u & 63) == 63) {                // flush h2 over consumed h1
            u32* dst = hbase + (size_t)(u - 63) * 64;
            *(uint4*)(dst + tid * 4) = *(const uint4*)(&och[tid * 4]);
            __syncthreads();
        }
    }
}

// ===================== layer 1 full (fallback if ws too small) ==============
__global__ __launch_bounds__(1024, 1) void k_l1full(
    u32* __restrict__ hws,
    const float* __restrict__ Wih, const float* __restrict__ Whh,
    const float* __restrict__ bih, const float* __restrict__ bhh,
    float* __restrict__ out)
{
    __shared__ u32 h1w[128 * 80];
    __shared__ u32 hp[2][80];
    __shared__ u32 och[4096];

    const int tid = threadIdx.x, b = blockIdx.x;
    const int m = tid >> 3, ksl = tid & 7;

    u32 w[64];
    float bias[4];
    const float* Wsel = (ksl < 4) ? Wih : Whh;
    const int colb = (ksl & 3) * 32;
#pragma unroll
    for (int g = 0; g < 4; ++g) {
        const int row = g * H_ + m;
        const float4* wr_ = (const float4*)(Wsel + row * H_ + colb);
#pragma unroll
        for (int j = 0; j < 8; ++j) {
            const float4 f = wr_[j];
            w[g * 16 + 2 * j]     = packh2(f.x, f.y);
            w[g * 16 + 2 * j + 1] = packh2(f.z, f.w);
        }
        bias[g] = bih[row] + bhh[row];
    }

    if (tid < 160) ((u32*)hp)[tid] = 0u;
    float c = 0.f;
    __syncthreads();

    u32* hbase = hws + (size_t)b * S_ * 64;
    for (int u = 0; u < S_; ++u) {
        if ((u & 127) == 0) {
            for (int i = tid; i < 2048; i += 1024) {
                const uint4 v = *(const uint4*)(hbase + (size_t)u * 64 + i * 4);
                const int st = i >> 4, p4 = i & 15;
                *(uint4*)(&h1w[st * 80 + (p4 >> 2) * 20 + (p4 & 3) * 4]) = v;
            }
            __syncthreads();
        }
        const u32* sel = (ksl < 4) ? &h1w[(u & 127) * 80 + ksl * 20]
                                   : &hp[(u + 1) & 1][(ksl - 4) * 20];
        float a0 = 0.f, a1 = 0.f, a2 = 0.f, a3 = 0.f;
#pragma unroll
        for (int p = 0; p < 4; ++p) {
            const uint4 v = *(const uint4*)(sel + p * 4);
            a0 = fdot2(v.x, w[4 * p], a0);      a0 = fdot2(v.y, w[4 * p + 1], a0);
            a0 = fdot2(v.z, w[4 * p + 2], a0);  a0 = fdot2(v.w, w[4 * p + 3], a0);
            a1 = fdot2(v.x, w[16 + 4 * p], a1); a1 = fdot2(v.y, w[17 + 4 * p], a1);
            a1 = fdot2(v.z, w[18 + 4 * p], a1); a1 = fdot2(v.w, w[19 + 4 * p], a1);
            a2 = fdot2(v.x, w[32 + 4 * p], a2); a2 = fdot2(v.y, w[33 + 4 * p], a2);
            a2 = fdot2(v.z, w[34 + 4 * p], a2); a2 = fdot2(v.w, w[35 + 4 * p], a2);
            a3 = fdot2(v.x, w[48 + 4 * p], a3); a3 = fdot2(v.y, w[49 + 4 * p], a3);
            a3 = fdot2(v.z, w[50 + 4 * p], a3); a3 = fdot2(v.w, w[51 + 4 * p], a3);
        }
        REDUCE8D(a0) REDUCE8D(a1) REDUCE8D(a2) REDUCE8D(a3)
        const float ig = sigm(a0 + bias[0]);
        const float fg = sigm(a1 + bias[1]);
        const float gc = tanh_(a2 + bias[2]);
        const float og = sigm(a3 + bias[3]);
        c = fg * c + ig * gc;
        const float hv = og * tanh_(c);
        const u32 pp = packh2(hv, dror8(hv));
        if ((tid & 15) == 0) {
            const int m2 = m >> 1;
            hp[u & 1][(m2 >> 4) * 20 + (m2 & 15)] = pp;
            och[(u & 63) * 64 + m2] = pp;
        }
        if (u == S_ - 1 && (tid & 7) == 0) {
            out[HH0 + 32768 + (size_t)b * H_ + m] = hv;
            out[HC0 + 32768 + (size_t)b * H_ + m] = c;
        }
        __syncthreads();
        if ((u & 63) == 63) {
            u32* dst = hbase + (size_t)(u - 63) * 64;
            *(uint4*)(dst + tid * 4) = *(const uint4*)(&och[tid * 4]);
            __syncthreads();
        }
    }
}

// ===================== heads: parallel over (b,s) ===========================
__global__ __launch_bounds__(256) void k_heads(
    const u32* __restrict__ h2p,
    const float* __restrict__ Wr1, const float* __restrict__ br1,
    const float* __restrict__ Wr2, const float* __restrict__ br2,
    const float* __restrict__ Wv1, const float* __restrict__ bv1,
    const float* __restrict__ Wv2, const float* __restrict__ bv2,
    float* __restrict__ out)
{
    __shared__ u32 wr[64 * 64], wv[64 * 64];
    __shared__ float w2r[64], w2v[64], b1r[64], b1v[64];

    const int tid = threadIdx.x;
    for (int i = tid; i < 4096; i += 256) {
        wr[i] = packh2(Wr1[2 * i], Wr1[2 * i + 1]);
        wv[i] = packh2(Wv1[2 * i], Wv1[2 * i + 1]);
    }
    if (tid < 64) {
        w2r[tid] = Wr2[tid]; w2v[tid] = Wv2[tid];
        b1r[tid] = br1[tid]; b1v[tid] = bv1[tid];
    }
    __syncthreads();

    const size_t bs = (size_t)blockIdx.x * 256 + tid;
    u32 hq[64];
    const u32* src = h2p + bs * 64;
#pragma unroll
    for (int j4 = 0; j4 < 16; ++j4) {
        const uint4 v = *(const uint4*)(src + j4 * 4);
        hq[j4 * 4] = v.x; hq[j4 * 4 + 1] = v.y; hq[j4 * 4 + 2] = v.z; hq[j4 * 4 + 3] = v.w;
    }
    float ret = br2[0], vol = bv2[0];
    for (int k = 0; k < 64; ++k) {
        float r = b1r[k], v = b1v[k];
#pragma unroll
        for (int j = 0; j < 64; ++j) r = fdot2(hq[j], wr[k * 64 + j], r);
#pragma unroll
        for (int j = 0; j < 64; ++j) v = fdot2(hq[j], wv[k * 64 + j], v);
        r = r > 0.f ? r : 0.01f * r;
        v = v > 0.f ? v : 0.01f * v;
        ret += r * w2r[k];
        vol += v * w2v[k];
    }
    out[RET0 + bs] = ret;
    out[VOL0 + bs] = softplus_(vol);
}

extern "C" void kernel_launch(void* const* d_in, const int* in_sizes, int n_in,
                              void* d_out, int out_size, void* d_ws, size_t ws_size,
                              hipStream_t stream) {
    (void)in_sizes; (void)n_in; (void)out_size;
    const float* x    = (const float*)d_in[0];
    const float* Wih0 = (const float*)d_in[1];
    const float* Whh0 = (const float*)d_in[2];
    const float* bih0 = (const float*)d_in[3];
    const float* bhh0 = (const float*)d_in[4];
    const float* Wih1 = (const float*)d_in[5];
    const float* Whh1 = (const float*)d_in[6];
    const float* bih1 = (const float*)d_in[7];
    const float* bhh1 = (const float*)d_in[8];
    const float* Wr1  = (const float*)d_in[9];
    const float* br1  = (const float*)d_in[10];
    const float* Wr2  = (const float*)d_in[11];
    const float* br2  = (const float*)d_in[12];
    const float* Wv1  = (const float*)d_in[13];
    const float* bv1  = (const float*)d_in[14];
    const float* Wv2  = (const float*)d_in[15];
    const float* bv2  = (const float*)d_in[16];
    u32* hws  = (u32*)d_ws;
    float* out = (float*)d_out;

    k_l0<<<B_, 1024, 0, stream>>>(x, Wih0, Whh0, bih0, bhh0, hws, out);
    if (ws_size >= WS_NEED) {
        u32* g1 = hws + G1OFF;
        k_g1<<<B_, 1024, 0, stream>>>(hws, Wih1, bih1, bhh1, g1);
        k_l1r<<<B_, 1024, 0, stream>>>(hws, g1, Whh1, out);
    } else {
        k_l1full<<<B_, 1024, 0, stream>>>(hws, Wih1, Whh1, bih1, bhh1, out);
    }
    k_heads<<<2048, 256, 0, stream>>>(hws, Wr1, br1, Wr2, br2,
                                      Wv1, bv1, Wv2, bv2, out);
}

// Round 12
// 3961.604 us; speedup vs baseline: 1.8528x; 1.0130x over previous
//
#include <hip/hip_runtime.h>
#include <hip/hip_bf16.h>

#define B_ 256
#define S_ 2048
#define D_ 16
#define H_ 128

typedef unsigned int u32;
typedef unsigned short u16;
typedef _Float16 h2t __attribute__((ext_vector_type(2)));

// ---- output layout (flat f32): returns | volatility | hidden_h | hidden_c
#define RET0 ((size_t)0)
#define VOL0 ((size_t)524288)
#define HH0  ((size_t)1048576)
#define HC0  ((size_t)1114112)

__device__ __forceinline__ float fdot2(u32 a, u32 b, float c) {
    return __builtin_amdgcn_fdot2(__builtin_bit_cast(h2t, a),
                                  __builtin_bit_cast(h2t, b), c, false);
}
__device__ __forceinline__ u32 packh2(float a, float b) {
    h2t h; h[0] = (_Float16)a; h[1] = (_Float16)b;
    return __builtin_bit_cast(u32, h);
}
__device__ __forceinline__ float sigm(float x) {
    return __builtin_amdgcn_rcpf(1.f + __builtin_amdgcn_exp2f(-1.44269504f * x));
}
__device__ __forceinline__ float tanh_(float x) {
    return 2.f * __builtin_amdgcn_rcpf(1.f + __builtin_amdgcn_exp2f(-2.88539008f * x)) - 1.f;
}
__device__ __forceinline__ float softplus_(float x) {
    if (x > 20.f) return x;
    const float e = __builtin_amdgcn_exp2f(1.44269504f * x);
    return 0.69314718f * __builtin_amdgcn_logf(1.f + e);
}
// all-VALU 8-lane reduction: quad_perm xor1, xor2, then row_half_mirror
__device__ __forceinline__ float dxor1(float a) {
    return __builtin_bit_cast(float, __builtin_amdgcn_update_dpp(
        0, __builtin_bit_cast(int, a), 0xB1, 0xF, 0xF, true));
}
__device__ __forceinline__ float dxor2(float a) {
    return __builtin_bit_cast(float, __builtin_amdgcn_update_dpp(
        0, __builtin_bit_cast(int, a), 0x4E, 0xF, 0xF, true));
}
__device__ __forceinline__ float dhalf(float a) {
    return __builtin_bit_cast(float, __builtin_amdgcn_update_dpp(
        0, __builtin_bit_cast(int, a), 0x141, 0xF, 0xF, true));
}
__device__ __forceinline__ float dror8(float a) {   // lane^8 within 16-lane row
    return __builtin_bit_cast(float, __builtin_amdgcn_update_dpp(
        0, __builtin_bit_cast(int, a), 0x128, 0xF, 0xF, true));
}
#define REDUCE8D(a) { a += dxor1(a); a += dxor2(a); a += dhalf(a); }

// ===================== layer 0 ==============================================
// 1024 thr: tid = m*8 + ksl. Thread: all 4 gates of unit m over K-eighth ksl.
// waves_per_eu(4,4): grid==CU count -> occupancy fixed at 4 waves/EU; give the
// allocator the full 128-VGPR budget so weights stay in arch VGPRs (no AGPR
// round-trips).
__global__
__attribute__((amdgpu_waves_per_eu(4, 4)))
__launch_bounds__(1024) void k_l0(
    const float* __restrict__ x, const float* __restrict__ Wih,
    const float* __restrict__ Whh, const float* __restrict__ bih,
    const float* __restrict__ bhh, u32* __restrict__ h1out,
    float* __restrict__ out)
{
    __shared__ u32 xp2[2][4096];   // 512-step x window, f16 pairs (32KB)
    __shared__ u32 hb[2][64];      // h1 state double buffer (f16 pairs)
    __shared__ u32 och[4096];      // 64-step h1 output staging (16KB)

    const int tid = threadIdx.x, b = blockIdx.x;
    const int m = tid >> 3, ksl = tid & 7;

    u32 wx[4], wh[32];
    float bias[4];
#pragma unroll
    for (int g = 0; g < 4; ++g) {
        const int row = g * H_ + m;
        const float2 f2 = *(const float2*)(Wih + row * D_ + ksl * 2);
        wx[g] = packh2(f2.x, f2.y);
        const float4* whr = (const float4*)(Whh + row * H_ + ksl * 16);
#pragma unroll
        for (int j = 0; j < 4; ++j) {
            const float4 f = whr[j];
            wh[g * 8 + 2 * j]     = packh2(f.x, f.y);
            wh[g * 8 + 2 * j + 1] = packh2(f.z, f.w);
        }
        bias[g] = bih[row] + bhh[row];
    }

    const float* xb = x + (size_t)b * S_ * D_;
    for (int i = tid; i < 2048; i += 1024) {
        const float4 v = *(const float4*)(xb + i * 4);
        xp2[0][2 * i] = packh2(v.x, v.y);
        xp2[0][2 * i + 1] = packh2(v.z, v.w);
    }
    if (tid < 128) ((u32*)hb)[tid] = 0u;
    float c = 0.f;
    __syncthreads();

    for (int t = 0; t < S_; ++t) {
        if ((t & 511) == 0 && t < S_ - 512) {
            const int nw = (t >> 9) + 1;
            u32* dst = xp2[nw & 1];
            const float* src = xb + (size_t)nw * 8192;
            for (int i = tid; i < 2048; i += 1024) {
                const float4 v = *(const float4*)(src + i * 4);
                dst[2 * i] = packh2(v.x, v.y);
                dst[2 * i + 1] = packh2(v.z, v.w);
            }
        }
        const u32 xv = xp2[(t >> 9) & 1][(t & 511) * 8 + ksl];
        const u32* hsel = &hb[(t + 1) & 1][ksl * 8];
        const uint4 h0 = *(const uint4*)(hsel);
        const uint4 h1v = *(const uint4*)(hsel + 4);

        float a0 = fdot2(xv, wx[0], 0.f), a1 = fdot2(xv, wx[1], 0.f);
        float a2 = fdot2(xv, wx[2], 0.f), a3 = fdot2(xv, wx[3], 0.f);
#define L0G(comp, j)                                                           \
        a0 = fdot2(comp, wh[j], a0);        a1 = fdot2(comp, wh[8 + (j)], a1); \
        a2 = fdot2(comp, wh[16 + (j)], a2); a3 = fdot2(comp, wh[24 + (j)], a3);
        L0G(h0.x, 0) L0G(h0.y, 1) L0G(h0.z, 2) L0G(h0.w, 3)
        L0G(h1v.x, 4) L0G(h1v.y, 5) L0G(h1v.z, 6) L0G(h1v.w, 7)
#undef L0G
        REDUCE8D(a0) REDUCE8D(a1) REDUCE8D(a2) REDUCE8D(a3)
        const float ig = sigm(a0 + bias[0]);
        const float fg = sigm(a1 + bias[1]);
        const float gc = tanh_(a2 + bias[2]);
        const float og = sigm(a3 + bias[3]);
        c = fg * c + ig * gc;
        const float hv = og * tanh_(c);
        const u32 pp = packh2(hv, dror8(hv));
        if ((tid & 15) == 0) {                   // ksl==0 && m even
            hb[t & 1][m >> 1] = pp;
            och[(t & 63) * 64 + (m >> 1)] = pp;
        }
        if (t == S_ - 1 && (tid & 7) == 0) {
            out[HH0 + (size_t)b * H_ + m] = hv;
            out[HC0 + (size_t)b * H_ + m] = c;
        }
        __syncthreads();
        if ((t & 63) == 63) {                    // flush 64 h1 rows
            u32* dst = h1out + ((size_t)b * S_ + (t - 63)) * 64;
            *(uint4*)(dst + tid * 4) = *(const uint4*)(&och[tid * 4]);
            __syncthreads();
        }
    }
}

// ===================== layer 1 ==============================================
// tid = m*8 + ksl. K = [h1: chunks 0-3][h2: chunks 0-3], 16 pairs per chunk.
// Padded chunk stride 20 u32 kills the 4-way bank conflict.
__global__
__attribute__((amdgpu_waves_per_eu(4, 4)))
__launch_bounds__(1024) void k_l1full(
    u32* __restrict__ hws,
    const float* __restrict__ Wih, const float* __restrict__ Whh,
    const float* __restrict__ bih, const float* __restrict__ bhh,
    float* __restrict__ out)
{
    __shared__ u32 h1w[128 * 80];  // 128-step h1 window, padded chunks (40KB)
    __shared__ u32 hp[2][80];      // h2 state dbuf, padded chunks of 20
    __shared__ u32 och[4096];      // 64-step h2 staging (16KB)

    const int tid = threadIdx.x, b = blockIdx.x;
    const int m = tid >> 3, ksl = tid & 7;

    u32 w[64];
    float bias[4];
    const float* Wsel = (ksl < 4) ? Wih : Whh;
    const int colb = (ksl & 3) * 32;
#pragma unroll
    for (int g = 0; g < 4; ++g) {
        const int row = g * H_ + m;
        const float4* wr_ = (const float4*)(Wsel + row * H_ + colb);
#pragma unroll
        for (int j = 0; j < 8; ++j) {
            const float4 f = wr_[j];
            w[g * 16 + 2 * j]     = packh2(f.x, f.y);
            w[g * 16 + 2 * j + 1] = packh2(f.z, f.w);
        }
        bias[g] = bih[row] + bhh[row];
    }

    if (tid < 160) ((u32*)hp)[tid] = 0u;
    float c = 0.f;
    __syncthreads();

    u32* hbase = hws + (size_t)b * S_ * 64;
    for (int u = 0; u < S_; ++u) {
        if ((u & 127) == 0) {                    // stage 128-step h1 window
            for (int i = tid; i < 2048; i += 1024) {
                const uint4 v = *(const uint4*)(hbase + (size_t)u * 64 + i * 4);
                const int st = i >> 4, p4 = i & 15;
                *(uint4*)(&h1w[st * 80 + (p4 >> 2) * 20 + (p4 & 3) * 4]) = v;
            }
            __syncthreads();
        }
        const u32* sel = (ksl < 4) ? &h1w[(u & 127) * 80 + ksl * 20]
                                   : &hp[(u + 1) & 1][(ksl - 4) * 20];
        float a0 = 0.f, a1 = 0.f, a2 = 0.f, a3 = 0.f;
#pragma unroll
        for (int p = 0; p < 4; ++p) {
            const uint4 v = *(const uint4*)(sel + p * 4);
            a0 = fdot2(v.x, w[4 * p], a0);      a0 = fdot2(v.y, w[4 * p + 1], a0);
            a0 = fdot2(v.z, w[4 * p + 2], a0);  a0 = fdot2(v.w, w[4 * p + 3], a0);
            a1 = fdot2(v.x, w[16 + 4 * p], a1); a1 = fdot2(v.y, w[17 + 4 * p], a1);
            a1 = fdot2(v.z, w[18 + 4 * p], a1); a1 = fdot2(v.w, w[19 + 4 * p], a1);
            a2 = fdot2(v.x, w[32 + 4 * p], a2); a2 = fdot2(v.y, w[33 + 4 * p], a2);
            a2 = fdot2(v.z, w[34 + 4 * p], a2); a2 = fdot2(v.w, w[35 + 4 * p], a2);
            a3 = fdot2(v.x, w[48 + 4 * p], a3); a3 = fdot2(v.y, w[49 + 4 * p], a3);
            a3 = fdot2(v.z, w[50 + 4 * p], a3); a3 = fdot2(v.w, w[51 + 4 * p], a3);
        }
        REDUCE8D(a0) REDUCE8D(a1) REDUCE8D(a2) REDUCE8D(a3)
        const float ig = sigm(a0 + bias[0]);
        const float fg = sigm(a1 + bias[1]);
        const float gc = tanh_(a2 + bias[2]);
        const float og = sigm(a3 + bias[3]);
        c = fg * c + ig * gc;
        const float hv = og * tanh_(c);
        const u32 pp = packh2(hv, dror8(hv));
        if ((tid & 15) == 0) {
            const int m2 = m >> 1;
            hp[u & 1][(m2 >> 4) * 20 + (m2 & 15)] = pp;
            och[(u & 63) * 64 + m2] = pp;
        }
        if (u == S_ - 1 && (tid & 7) == 0) {
            out[HH0 + 32768 + (size_t)b * H_ + m] = hv;
            out[HC0 + 32768 + (size_t)b * H_ + m] = c;
        }
        __syncthreads();
        if ((u & 63) == 63) {                    // flush h2 over consumed h1
            u32* dst = hbase + (size_t)(u - 63) * 64;
            *(uint4*)(dst + tid * 4) = *(const uint4*)(&och[tid * 4]);
            __syncthreads();
        }
    }
}

// ===================== heads: parallel over (b,s) ===========================
__global__
__attribute__((amdgpu_waves_per_eu(4, 4)))
__launch_bounds__(256) void k_heads(
    const u32* __restrict__ h2p,
    const float* __restrict__ Wr1, const float* __restrict__ br1,
    const float* __restrict__ Wr2, const float* __restrict__ br2,
    const float* __restrict__ Wv1, const float* __restrict__ bv1,
    const float* __restrict__ Wv2, const float* __restrict__ bv2,
    float* __restrict__ out)
{
    __shared__ u32 wr[64 * 64], wv[64 * 64];
    __shared__ float w2r[64], w2v[64], b1r[64], b1v[64];

    const int tid = threadIdx.x;
    for (int i = tid; i < 4096; i += 256) {
        wr[i] = packh2(Wr1[2 * i], Wr1[2 * i + 1]);
        wv[i] = packh2(Wv1[2 * i], Wv1[2 * i + 1]);
    }
    if (tid < 64) {
        w2r[tid] = Wr2[tid]; w2v[tid] = Wv2[tid];
        b1r[tid] = br1[tid]; b1v[tid] = bv1[tid];
    }
    __syncthreads();

    const size_t bs = (size_t)blockIdx.x * 256 + tid;
    u32 hq[64];
    const u32* src = h2p + bs * 64;
#pragma unroll
    for (int j4 = 0; j4 < 16; ++j4) {
        const uint4 v = *(const uint4*)(src + j4 * 4);
        hq[j4 * 4] = v.x; hq[j4 * 4 + 1] = v.y; hq[j4 * 4 + 2] = v.z; hq[j4 * 4 + 3] = v.w;
    }
    float ret = br2[0], vol = bv2[0];
    for (int k = 0; k < 64; ++k) {
        float r = b1r[k], v = b1v[k];
#pragma unroll
        for (int j = 0; j < 64; ++j) r = fdot2(hq[j], wr[k * 64 + j], r);
#pragma unroll
        for (int j = 0; j < 64; ++j) v = fdot2(hq[j], wv[k * 64 + j], v);
        r = r > 0.f ? r : 0.01f * r;
        v = v > 0.f ? v : 0.01f * v;
        ret += r * w2r[k];
        vol += v * w2v[k];
    }
    out[RET0 + bs] = ret;
    out[VOL0 + bs] = softplus_(vol);
}

extern "C" void kernel_launch(void* const* d_in, const int* in_sizes, int n_in,
                              void* d_out, int out_size, void* d_ws, size_t ws_size,
                              hipStream_t stream) {
    (void)in_sizes; (void)n_in; (void)out_size; (void)ws_size;
    const float* x    = (const float*)d_in[0];
    const float* Wih0 = (const float*)d_in[1];
    const float* Whh0 = (const float*)d_in[2];
    const float* bih0 = (const float*)d_in[3];
    const float* bhh0 = (const float*)d_in[4];
    const float* Wih1 = (const float*)d_in[5];
    const float* Whh1 = (const float*)d_in[6];
    const float* bih1 = (const float*)d_in[7];
    const float* bhh1 = (const float*)d_in[8];
    const float* Wr1  = (const float*)d_in[9];
    const float* br1  = (const float*)d_in[10];
    const float* Wr2  = (const float*)d_in[11];
    const float* br2  = (const float*)d_in[12];
    const float* Wv1  = (const float*)d_in[13];
    const float* bv1  = (const float*)d_in[14];
    const float* Wv2  = (const float*)d_in[15];
    const float* bv2  = (const float*)d_in[16];
    u32* hws  = (u32*)d_ws;           // 134 MB: h1 pairs, then h2 in-place
    float* out = (float*)d_out;

    k_l0<<<B_, 1024, 0, stream>>>(x, Wih0, Whh0, bih0, bhh0, hws, out);
    k_l1full<<<B_, 1024, 0, stream>>>(hws, Wih1, Whh1, bih1, bhh1, out);
    k_heads<<<2048, 256, 0, stream>>>(hws, Wr1, br1, Wr2, br2,
                                      Wv1, bv1, Wv2, bv2, out);
}

// Round 13
// 3554.027 us; speedup vs baseline: 2.0653x; 1.1147x over previous
//
#include <hip/hip_runtime.h>
#include <hip/hip_bf16.h>

#define B_ 256
#define S_ 2048
#define D_ 16
#define H_ 128

typedef unsigned int u32;
typedef unsigned short u16;
typedef _Float16 h2t __attribute__((ext_vector_type(2)));

// ---- output layout (flat f32): returns | volatility | hidden_h | hidden_c
#define RET0 ((size_t)0)
#define VOL0 ((size_t)524288)
#define HH0  ((size_t)1048576)
#define HC0  ((size_t)1114112)

__device__ __forceinline__ float fdot2(u32 a, u32 b, float c) {
    return __builtin_amdgcn_fdot2(__builtin_bit_cast(h2t, a),
                                  __builtin_bit_cast(h2t, b), c, false);
}
__device__ __forceinline__ u32 packh2(float a, float b) {
    h2t h; h[0] = (_Float16)a; h[1] = (_Float16)b;
    return __builtin_bit_cast(u32, h);
}
__device__ __forceinline__ float sigm(float x) {
    return __builtin_amdgcn_rcpf(1.f + __builtin_amdgcn_exp2f(-1.44269504f * x));
}
__device__ __forceinline__ float tanh_(float x) {
    return 2.f * __builtin_amdgcn_rcpf(1.f + __builtin_amdgcn_exp2f(-2.88539008f * x)) - 1.f;
}
__device__ __forceinline__ float softplus_(float x) {
    if (x > 20.f) return x;
    const float e = __builtin_amdgcn_exp2f(1.44269504f * x);
    return 0.69314718f * __builtin_amdgcn_logf(1.f + e);
}
// DPP lane-neighbor value (quad_perm [1,0,3,2])
__device__ __forceinline__ float dnb1(float a) {
    return __builtin_bit_cast(float, __builtin_amdgcn_update_dpp(
        0, __builtin_bit_cast(int, a), 0xB1, 0xF, 0xF, true));
}

// ===================== layer 0 ==============================================
// 1024 thr: tid = ksl*128 + m (ksl-pure waves). Phase A: dots + one b128
// partial write. Phase B: waves 0-1 reduce 8 partials, activate ONCE.
__global__
__attribute__((amdgpu_waves_per_eu(4, 4)))
__launch_bounds__(1024) void k_l0(
    const float* __restrict__ x, const float* __restrict__ Wih,
    const float* __restrict__ Whh, const float* __restrict__ bih,
    const float* __restrict__ bhh, u32* __restrict__ h1out,
    float* __restrict__ out)
{
    __shared__ u32 xp2[2][2048];       // 2 x 256-step x window (16KB)
    __shared__ float gates[8][128][4]; // per-ksl gate partials (16KB)
    __shared__ u32 hb[2][64];          // h1 state dbuf (f16 pairs)
    __shared__ u32 och[2048];          // 32-step h1 staging (8KB)

    const int tid = threadIdx.x, b = blockIdx.x;
    const int ksl = tid >> 7, m = tid & 127;

    u32 wx[4], wh[32];
#pragma unroll
    for (int g = 0; g < 4; ++g) {
        const int row = g * H_ + m;
        const float2 f2 = *(const float2*)(Wih + row * D_ + ksl * 2);
        wx[g] = packh2(f2.x, f2.y);
        const float4* whr = (const float4*)(Whh + row * H_ + ksl * 16);
#pragma unroll
        for (int j = 0; j < 4; ++j) {
            const float4 f = whr[j];
            wh[g * 8 + 2 * j]     = packh2(f.x, f.y);
            wh[g * 8 + 2 * j + 1] = packh2(f.z, f.w);
        }
    }
    float bias[4], c = 0.f;
    if (tid < 128) {
#pragma unroll
        for (int g = 0; g < 4; ++g) bias[g] = bih[g * H_ + tid] + bhh[g * H_ + tid];
    }

    const float* xb = x + (size_t)b * S_ * D_;
    {   // stage window 0 (256 steps = 1024 float4, one per thread)
        const float4 v = *(const float4*)(xb + tid * 4);
        xp2[0][2 * tid] = packh2(v.x, v.y);
        xp2[0][2 * tid + 1] = packh2(v.z, v.w);
    }
    if (tid < 128) ((u32*)hb)[tid] = 0u;
    __syncthreads();

    for (int t = 0; t < S_; ++t) {
        if ((t & 255) == 0 && t < S_ - 256) {    // prefetch next x window
            const int nw = (t >> 8) + 1;
            const float4 v = *(const float4*)(xb + (size_t)nw * 4096 + tid * 4);
            xp2[nw & 1][2 * tid] = packh2(v.x, v.y);
            xp2[nw & 1][2 * tid + 1] = packh2(v.z, v.w);
        }
        // ---- phase A: dot products
        const u32 xv = xp2[(t >> 8) & 1][(t & 255) * 8 + ksl];
        const u32* hs = &hb[(t + 1) & 1][ksl * 8];
        const uint4 h0 = *(const uint4*)(hs);
        const uint4 h1v = *(const uint4*)(hs + 4);
        float a0 = fdot2(xv, wx[0], 0.f), a1 = fdot2(xv, wx[1], 0.f);
        float a2 = fdot2(xv, wx[2], 0.f), a3 = fdot2(xv, wx[3], 0.f);
#define L0G(comp, j)                                                           \
        a0 = fdot2(comp, wh[j], a0);        a1 = fdot2(comp, wh[8 + (j)], a1); \
        a2 = fdot2(comp, wh[16 + (j)], a2); a3 = fdot2(comp, wh[24 + (j)], a3);
        L0G(h0.x, 0) L0G(h0.y, 1) L0G(h0.z, 2) L0G(h0.w, 3)
        L0G(h1v.x, 4) L0G(h1v.y, 5) L0G(h1v.z, 6) L0G(h1v.w, 7)
#undef L0G
        float4 part; part.x = a0; part.y = a1; part.z = a2; part.w = a3;
        *(float4*)&gates[ksl][m][0] = part;
        __syncthreads();
        // ---- phase B: waves 0-1 reduce + activate once
        if (tid < 128) {
            float4 s = *(const float4*)&gates[0][tid][0];
#pragma unroll
            for (int k = 1; k < 8; ++k) {
                const float4 p = *(const float4*)&gates[k][tid][0];
                s.x += p.x; s.y += p.y; s.z += p.z; s.w += p.w;
            }
            const float ig = sigm(s.x + bias[0]);
            const float fg = sigm(s.y + bias[1]);
            const float gc = tanh_(s.z + bias[2]);
            const float og = sigm(s.w + bias[3]);
            c = fg * c + ig * gc;
            const float hv = og * tanh_(c);
            const u32 pp = packh2(hv, dnb1(hv));
            if (!(tid & 1)) {
                hb[t & 1][tid >> 1] = pp;
                och[(t & 31) * 64 + (tid >> 1)] = pp;
            }
            if (t == S_ - 1) {
                out[HH0 + (size_t)b * H_ + tid] = hv;
                out[HC0 + (size_t)b * H_ + tid] = c;
            }
        }
        __syncthreads();
        if ((t & 31) == 31) {                    // flush 32 h1 rows
            if (tid < 512) {
                u32* dst = h1out + ((size_t)b * S_ + (t - 31)) * 64;
                *(uint4*)(dst + tid * 4) = *(const uint4*)(&och[tid * 4]);
            }
            __syncthreads();
        }
    }
}

// ===================== layer 1 ==============================================
// tid = ksl*128 + m. K-concat [h1|h2]: ksl<4 -> h1 window, ksl>=4 -> h2 state.
__global__
__attribute__((amdgpu_waves_per_eu(4, 4)))
__launch_bounds__(1024) void k_l1(
    u32* __restrict__ hws,
    const float* __restrict__ Wih, const float* __restrict__ Whh,
    const float* __restrict__ bih, const float* __restrict__ bhh,
    float* __restrict__ out)
{
    __shared__ u32 h1w[64 * 80];       // 64-step h1 window, padded (20KB)
    __shared__ float gates[8][128][4]; // gate partials (16KB)
    __shared__ u32 hp[2][80];          // h2 state dbuf, padded
    __shared__ u32 och[2048];          // 32-step h2 staging (8KB)

    const int tid = threadIdx.x, b = blockIdx.x;
    const int ksl = tid >> 7, m = tid & 127;

    u32 w[64];
    const float* Wsel = (ksl < 4) ? Wih : Whh;
    const int colb = (ksl & 3) * 32;
#pragma unroll
    for (int g = 0; g < 4; ++g) {
        const int row = g * H_ + m;
        const float4* wr_ = (const float4*)(Wsel + row * H_ + colb);
#pragma unroll
        for (int j = 0; j < 8; ++j) {
            const float4 f = wr_[j];
            w[g * 16 + 2 * j]     = packh2(f.x, f.y);
            w[g * 16 + 2 * j + 1] = packh2(f.z, f.w);
        }
    }
    float bias[4], c = 0.f;
    if (tid < 128) {
#pragma unroll
        for (int g = 0; g < 4; ++g) bias[g] = bih[g * H_ + tid] + bhh[g * H_ + tid];
    }
    if (tid < 160) ((u32*)hp)[tid] = 0u;
    __syncthreads();

    u32* hbase = hws + (size_t)b * S_ * 64;
    for (int u = 0; u < S_; ++u) {
        if ((u & 63) == 0) {                     // stage 64-step h1 window
            const uint4 v = *(const uint4*)(hbase + (size_t)u * 64 + tid * 4);
            const int st = tid >> 4, p4 = tid & 15;
            *(uint4*)(&h1w[st * 80 + (p4 >> 2) * 20 + (p4 & 3) * 4]) = v;
            __syncthreads();
        }
        // ---- phase A
        const u32* sel = (ksl < 4) ? &h1w[(u & 63) * 80 + ksl * 20]
                                   : &hp[(u + 1) & 1][(ksl - 4) * 20];
        float a0 = 0.f, a1 = 0.f, a2 = 0.f, a3 = 0.f;
#pragma unroll
        for (int p = 0; p < 4; ++p) {
            const uint4 v = *(const uint4*)(sel + p * 4);
            a0 = fdot2(v.x, w[4 * p], a0);      a0 = fdot2(v.y, w[4 * p + 1], a0);
            a0 = fdot2(v.z, w[4 * p + 2], a0);  a0 = fdot2(v.w, w[4 * p + 3], a0);
            a1 = fdot2(v.x, w[16 + 4 * p], a1); a1 = fdot2(v.y, w[17 + 4 * p], a1);
            a1 = fdot2(v.z, w[18 + 4 * p], a1); a1 = fdot2(v.w, w[19 + 4 * p], a1);
            a2 = fdot2(v.x, w[32 + 4 * p], a2); a2 = fdot2(v.y, w[33 + 4 * p], a2);
            a2 = fdot2(v.z, w[34 + 4 * p], a2); a2 = fdot2(v.w, w[35 + 4 * p], a2);
            a3 = fdot2(v.x, w[48 + 4 * p], a3); a3 = fdot2(v.y, w[49 + 4 * p], a3);
            a3 = fdot2(v.z, w[50 + 4 * p], a3); a3 = fdot2(v.w, w[51 + 4 * p], a3);
        }
        float4 part; part.x = a0; part.y = a1; part.z = a2; part.w = a3;
        *(float4*)&gates[ksl][m][0] = part;
        __syncthreads();
        // ---- phase B
        if (tid < 128) {
            float4 s = *(const float4*)&gates[0][tid][0];
#pragma unroll
            for (int k = 1; k < 8; ++k) {
                const float4 p = *(const float4*)&gates[k][tid][0];
                s.x += p.x; s.y += p.y; s.z += p.z; s.w += p.w;
            }
            const float ig = sigm(s.x + bias[0]);
            const float fg = sigm(s.y + bias[1]);
            const float gc = tanh_(s.z + bias[2]);
            const float og = sigm(s.w + bias[3]);
            c = fg * c + ig * gc;
            const float hv = og * tanh_(c);
            const u32 pp = packh2(hv, dnb1(hv));
            if (!(tid & 1)) {
                const int p2 = tid >> 1;
                hp[u & 1][(p2 >> 4) * 20 + (p2 & 15)] = pp;
                och[(u & 31) * 64 + p2] = pp;
            }
            if (u == S_ - 1) {
                out[HH0 + 32768 + (size_t)b * H_ + tid] = hv;
                out[HC0 + 32768 + (size_t)b * H_ + tid] = c;
            }
        }
        __syncthreads();
        if ((u & 31) == 31) {                    // flush h2 over consumed h1
            if (tid < 512) {
                u32* dst = hbase + (size_t)(u - 31) * 64;
                *(uint4*)(dst + tid * 4) = *(const uint4*)(&och[tid * 4]);
            }
            __syncthreads();
        }
    }
}

// ===================== heads: parallel over (b,s) ===========================
__global__ __launch_bounds__(256) void k_heads(
    const u32* __restrict__ h2p,
    const float* __restrict__ Wr1, const float* __restrict__ br1,
    const float* __restrict__ Wr2, const float* __restrict__ br2,
    const float* __restrict__ Wv1, const float* __restrict__ bv1,
    const float* __restrict__ Wv2, const float* __restrict__ bv2,
    float* __restrict__ out)
{
    __shared__ u32 wr[64 * 64], wv[64 * 64];
    __shared__ float w2r[64], w2v[64], b1r[64], b1v[64];

    const int tid = threadIdx.x;
    for (int i = tid; i < 4096; i += 256) {
        wr[i] = packh2(Wr1[2 * i], Wr1[2 * i + 1]);
        wv[i] = packh2(Wv1[2 * i], Wv1[2 * i + 1]);
    }
    if (tid < 64) {
        w2r[tid] = Wr2[tid]; w2v[tid] = Wv2[tid];
        b1r[tid] = br1[tid]; b1v[tid] = bv1[tid];
    }
    __syncthreads();

    const size_t bs = (size_t)blockIdx.x * 256 + tid;
    u32 hq[64];
    const u32* src = h2p + bs * 64;
#pragma unroll
    for (int j4 = 0; j4 < 16; ++j4) {
        const uint4 v = *(const uint4*)(src + j4 * 4);
        hq[j4 * 4] = v.x; hq[j4 * 4 + 1] = v.y; hq[j4 * 4 + 2] = v.z; hq[j4 * 4 + 3] = v.w;
    }
    float ret = br2[0], vol = bv2[0];
    for (int k = 0; k < 64; ++k) {
        float r = b1r[k], v = b1v[k];
#pragma unroll
        for (int j = 0; j < 64; ++j) r = fdot2(hq[j], wr[k * 64 + j], r);
#pragma unroll
        for (int j = 0; j < 64; ++j) v = fdot2(hq[j], wv[k * 64 + j], v);
        r = r > 0.f ? r : 0.01f * r;
        v = v > 0.f ? v : 0.01f * v;
        ret += r * w2r[k];
        vol += v * w2v[k];
    }
    out[RET0 + bs] = ret;
    out[VOL0 + bs] = softplus_(vol);
}

extern "C" void kernel_launch(void* const* d_in, const int* in_sizes, int n_in,
                              void* d_out, int out_size, void* d_ws, size_t ws_size,
                              hipStream_t stream) {
    (void)in_sizes; (void)n_in; (void)out_size; (void)ws_size;
    const float* x    = (const float*)d_in[0];
    const float* Wih0 = (const float*)d_in[1];
    const float* Whh0 = (const float*)d_in[2];
    const float* bih0 = (const float*)d_in[3];
    const float* bhh0 = (const float*)d_in[4];
    const float* Wih1 = (const float*)d_in[5];
    const float* Whh1 = (const float*)d_in[6];
    const float* bih1 = (const float*)d_in[7];
    const float* bhh1 = (const float*)d_in[8];
    const float* Wr1  = (const float*)d_in[9];
    const float* br1  = (const float*)d_in[10];
    const float* Wr2  = (const float*)d_in[11];
    const float* br2  = (const float*)d_in[12];
    const float* Wv1  = (const float*)d_in[13];
    const float* bv1  = (const float*)d_in[14];
    const float* Wv2  = (const float*)d_in[15];
    const float* bv2  = (const float*)d_in[16];
    u32* hws  = (u32*)d_ws;           // 134 MB: h1 pairs, then h2 in-place
    float* out = (float*)d_out;

    k_l0<<<B_, 1024, 0, stream>>>(x, Wih0, Whh0, bih0, bhh0, hws, out);
    k_l1<<<B_, 1024, 0, stream>>>(hws, Wih1, Whh1, bih1, bhh1, out);
    k_heads<<<2048, 256, 0, stream>>>(hws, Wr1, br1, Wr2, br2,
                                      Wv1, bv1, Wv2, bv2, out);
}

// Round 14
// 3437.566 us; speedup vs baseline: 2.1352x; 1.0339x over previous
//
#include <hip/hip_runtime.h>
#include <hip/hip_bf16.h>

#define B_ 256
#define S_ 2048
#define D_ 16
#define H_ 128

typedef unsigned int u32;
typedef _Float16 h2t __attribute__((ext_vector_type(2)));

// ---- output layout (flat f32): returns | volatility | hidden_h | hidden_c
#define RET0 ((size_t)0)
#define VOL0 ((size_t)524288)
#define HH0  ((size_t)1048576)
#define HC0  ((size_t)1114112)

__device__ __forceinline__ float fdot2(u32 a, u32 b, float c) {
    return __builtin_amdgcn_fdot2(__builtin_bit_cast(h2t, a),
                                  __builtin_bit_cast(h2t, b), c, false);
}
__device__ __forceinline__ u32 packh2(float a, float b) {
    h2t h; h[0] = (_Float16)a; h[1] = (_Float16)b;
    return __builtin_bit_cast(u32, h);
}
__device__ __forceinline__ float sigm(float x) {
    return __builtin_amdgcn_rcpf(1.f + __builtin_amdgcn_exp2f(-1.44269504f * x));
}
__device__ __forceinline__ float tanh_(float x) {
    return 2.f * __builtin_amdgcn_rcpf(1.f + __builtin_amdgcn_exp2f(-2.88539008f * x)) - 1.f;
}
__device__ __forceinline__ float softplus_(float x) {
    if (x > 20.f) return x;
    const float e = __builtin_amdgcn_exp2f(1.44269504f * x);
    return 0.69314718f * __builtin_amdgcn_logf(1.f + e);
}
// DPP lane^1 neighbor (quad_perm [1,0,3,2])
__device__ __forceinline__ float dnb1(float a) {
    return __builtin_bit_cast(float, __builtin_amdgcn_update_dpp(
        0, __builtin_bit_cast(int, a), 0xB1, 0xF, 0xF, true));
}

// ===================== layer 0 ==============================================
// 512 thr = 8 waves. A: tid = ksl*128 + m; thread computes 4 gate-rows of unit
// m over K-quarter ksl (x pairs [2ksl,+2), h pairs [16ksl,+16)). One barrier
// per step; B: each wave activates ONLY the units whose h-pairs it reads next
// step (private hb[wave] slice) -> no B->A cross-wave dependency.
__global__ __launch_bounds__(512, 2) void k_l0(
    const float* __restrict__ x, const float* __restrict__ Wih,
    const float* __restrict__ Whh, const float* __restrict__ bih,
    const float* __restrict__ bhh, u32* __restrict__ h1out,
    float* __restrict__ out)
{
    __shared__ u32 xp2[2][2048];          // 2 x 256-step x window (16KB)
    __shared__ float gates[2][4][128][4]; // dbuf gate partials (16KB)
    __shared__ u32 hb[8][16];             // per-wave private h1 pair slice
    __shared__ u32 och[2][2048];          // dbuf 32-step staging (16KB)

    const int tid = threadIdx.x, b = blockIdx.x;
    const int ksl = tid >> 7, m = tid & 127;
    const int wv = tid >> 6, j = tid & 63;
    const int unit = (ksl << 5) + (j & 31);

    u32 wx[8], wh[64];
#pragma unroll
    for (int g = 0; g < 4; ++g) {
        const int row = g * H_ + m;
        const float4 fx = *(const float4*)(Wih + row * D_ + ksl * 4);
        wx[g * 2]     = packh2(fx.x, fx.y);
        wx[g * 2 + 1] = packh2(fx.z, fx.w);
        const float4* whr = (const float4*)(Whh + row * H_ + ksl * 32);
#pragma unroll
        for (int q = 0; q < 8; ++q) {
            const float4 f = whr[q];
            wh[g * 16 + 2 * q]     = packh2(f.x, f.y);
            wh[g * 16 + 2 * q + 1] = packh2(f.z, f.w);
        }
    }
    const float bias0 = bih[unit] + bhh[unit];
    const float bias1 = bih[128 + unit] + bhh[128 + unit];
    const float bias2 = bih[256 + unit] + bhh[256 + unit];
    const float bias3 = bih[384 + unit] + bhh[384 + unit];

    const float* xb = x + (size_t)b * S_ * D_;
#pragma unroll
    for (int k = 0; k < 2; ++k) {         // stage x window 0
        const int i = tid + k * 512;
        const float4 v = *(const float4*)(xb + i * 4);
        xp2[0][2 * i]     = packh2(v.x, v.y);
        xp2[0][2 * i + 1] = packh2(v.z, v.w);
    }
    if (tid < 128) ((u32*)hb)[tid] = 0u;
    float c = 0.f;
    __syncthreads();

    for (int t = 0; t < S_; ++t) {
        if ((t & 255) == 0 && t < S_ - 256) {   // prefetch next x window
            const int nw = (t >> 8) + 1;
#pragma unroll
            for (int k = 0; k < 2; ++k) {
                const int i = tid + k * 512;
                const float4 v = *(const float4*)(xb + (size_t)nw * 4096 + i * 4);
                xp2[nw & 1][2 * i]     = packh2(v.x, v.y);
                xp2[nw & 1][2 * i + 1] = packh2(v.z, v.w);
            }
        }
        // ---- A: dots on this wave's private slice
        const uint2 xv = *(const uint2*)&xp2[(t >> 8) & 1][(t & 255) * 8 + ksl * 2];
        const uint4* hq = (const uint4*)hb[wv];
        const uint4 h0 = hq[0], h1 = hq[1], h2 = hq[2], h3 = hq[3];
        float a0 = fdot2(xv.x, wx[0], 0.f); a0 = fdot2(xv.y, wx[1], a0);
        float a1 = fdot2(xv.x, wx[2], 0.f); a1 = fdot2(xv.y, wx[3], a1);
        float a2 = fdot2(xv.x, wx[4], 0.f); a2 = fdot2(xv.y, wx[5], a2);
        float a3 = fdot2(xv.x, wx[6], 0.f); a3 = fdot2(xv.y, wx[7], a3);
#define DG(vv, p)                                                              \
        a0 = fdot2(vv, wh[p], a0);        a1 = fdot2(vv, wh[16 + (p)], a1);    \
        a2 = fdot2(vv, wh[32 + (p)], a2); a3 = fdot2(vv, wh[48 + (p)], a3);
        DG(h0.x, 0) DG(h0.y, 1) DG(h0.z, 2) DG(h0.w, 3)
        DG(h1.x, 4) DG(h1.y, 5) DG(h1.z, 6) DG(h1.w, 7)
        DG(h2.x, 8) DG(h2.y, 9) DG(h2.z, 10) DG(h2.w, 11)
        DG(h3.x, 12) DG(h3.y, 13) DG(h3.z, 14) DG(h3.w, 15)
#undef DG
        float4 part; part.x = a0; part.y = a1; part.z = a2; part.w = a3;
        *(float4*)&gates[t & 1][ksl][m][0] = part;
        __syncthreads();                       // the ONLY barrier per step
        // ---- B (all waves; each owns units [32ksl, 32ksl+32))
        if ((t & 31) == 0 && t) {              // flush previous och window
            u32* dst = h1out + ((size_t)b * S_ + (t - 32)) * 64;
            *(uint4*)(dst + tid * 4) = *(const uint4*)&och[((t >> 5) & 1) ^ 1][tid * 4];
        }
        const float4 s0 = *(const float4*)&gates[t & 1][0][unit][0];
        const float4 s1 = *(const float4*)&gates[t & 1][1][unit][0];
        const float4 s2 = *(const float4*)&gates[t & 1][2][unit][0];
        const float4 s3 = *(const float4*)&gates[t & 1][3][unit][0];
        const float ig = sigm((s0.x + s1.x) + (s2.x + s3.x) + bias0);
        const float fg = sigm((s0.y + s1.y) + (s2.y + s3.y) + bias1);
        const float gc = tanh_((s0.z + s1.z) + (s2.z + s3.z) + bias2);
        const float og = sigm((s0.w + s1.w) + (s2.w + s3.w) + bias3);
        c = fg * c + ig * gc;
        const float h = og * tanh_(c);
        const u32 pp = packh2(h, dnb1(h));
        if ((j & 33) == 0) {                   // j<32 && even
            hb[wv][j >> 1] = pp;               // private slice for next A
            if (!(wv & 1)) och[(t >> 5) & 1][(t & 31) * 64 + (unit >> 1)] = pp;
        }
        if (t == S_ - 1 && !(wv & 1) && j < 32) {
            out[HH0 + (size_t)b * H_ + unit] = h;
            out[HC0 + (size_t)b * H_ + unit] = c;
        }
    }
    __syncthreads();
    {   // final flush: steps [2016, 2048), och buffer 1
        u32* dst = h1out + ((size_t)b * S_ + (S_ - 32)) * 64;
        *(uint4*)(dst + tid * 4) = *(const uint4*)&och[1][tid * 4];
    }
}

// ===================== layer 1 ==============================================
// A: ksl<2 -> W_ih . h1 (window), ksl>=2 -> W_hh . h2 (private hb). B: waves
// 4-7 activate (1 unit/lane); waves 0-1 do och flush + window staging.
__global__ __launch_bounds__(512, 2) void k_l1(
    u32* __restrict__ hws,
    const float* __restrict__ Wih, const float* __restrict__ Whh,
    const float* __restrict__ bih, const float* __restrict__ bhh,
    float* __restrict__ out)
{
    __shared__ u32 h1w[2][5120];          // dbuf 64-step padded window (40KB)
    __shared__ float gates[2][4][128][4]; // dbuf gate partials (16KB)
    __shared__ u32 hb[8][32];             // per-wave private h2 pairs (1KB)
    __shared__ u32 och[2][2048];          // dbuf staging (16KB)

    const int tid = threadIdx.x, b = blockIdx.x;
    const int ksl = tid >> 7, m = tid & 127;
    const int wv = tid >> 6, j = tid & 63;
    const int unit = ((ksl & 1) << 6) + j;   // B-phase unit (ksl>=2)

    u32 w[128];
    const float* Wsel = (ksl < 2) ? Wih : Whh;
    const int eb = (ksl & 1) * 64;           // element base within matrix row
#pragma unroll
    for (int g = 0; g < 4; ++g) {
        const int row = g * H_ + m;
        const float4* wr_ = (const float4*)(Wsel + row * H_ + eb);
#pragma unroll
        for (int q = 0; q < 16; ++q) {
            const float4 f = wr_[q];
            w[g * 32 + 2 * q]     = packh2(f.x, f.y);
            w[g * 32 + 2 * q + 1] = packh2(f.z, f.w);
        }
    }
    const float bias0 = bih[unit] + bhh[unit];
    const float bias1 = bih[128 + unit] + bhh[128 + unit];
    const float bias2 = bih[256 + unit] + bhh[256 + unit];
    const float bias3 = bih[384 + unit] + bhh[384 + unit];

    u32* hbase = hws + (size_t)b * S_ * 64;
#pragma unroll
    for (int k = 0; k < 2; ++k) {            // stage window 0 (padded)
        const int i = tid + k * 512;
        const uint4 v = *(const uint4*)(hbase + i * 4);
        *(uint4*)&h1w[0][(i >> 4) * 80 + ((i & 15) >> 2) * 20 + (i & 3) * 4] = v;
    }
    if (tid < 256) ((u32*)hb)[tid] = 0u;
    float c = 0.f;
    __syncthreads();

    for (int u = 0; u < S_; ++u) {
        // ---- A
        uint4 v0, v1, v2, v3, v4, v5, v6, v7;
        if (ksl < 2) {
            const u32* src = &h1w[(u >> 6) & 1][(u & 63) * 80 + ksl * 40];
            v0 = *(const uint4*)(src);      v1 = *(const uint4*)(src + 4);
            v2 = *(const uint4*)(src + 8);  v3 = *(const uint4*)(src + 12);
            v4 = *(const uint4*)(src + 20); v5 = *(const uint4*)(src + 24);
            v6 = *(const uint4*)(src + 28); v7 = *(const uint4*)(src + 32);
        } else {
            const u32* src = hb[wv];
            v0 = *(const uint4*)(src);      v1 = *(const uint4*)(src + 4);
            v2 = *(const uint4*)(src + 8);  v3 = *(const uint4*)(src + 12);
            v4 = *(const uint4*)(src + 16); v5 = *(const uint4*)(src + 20);
            v6 = *(const uint4*)(src + 24); v7 = *(const uint4*)(src + 28);
        }
        float a0 = 0.f, a1 = 0.f, a2 = 0.f, a3 = 0.f;
#define DQ(vv, q4)                                                             \
        a0 = fdot2(vv.x, w[q4], a0);          a0 = fdot2(vv.y, w[(q4)+1], a0); \
        a0 = fdot2(vv.z, w[(q4)+2], a0);      a0 = fdot2(vv.w, w[(q4)+3], a0); \
        a1 = fdot2(vv.x, w[32+(q4)], a1);     a1 = fdot2(vv.y, w[33+(q4)], a1);\
        a1 = fdot2(vv.z, w[34+(q4)], a1);     a1 = fdot2(vv.w, w[35+(q4)], a1);\
        a2 = fdot2(vv.x, w[64+(q4)], a2);     a2 = fdot2(vv.y, w[65+(q4)], a2);\
        a2 = fdot2(vv.z, w[66+(q4)], a2);     a2 = fdot2(vv.w, w[67+(q4)], a2);\
        a3 = fdot2(vv.x, w[96+(q4)], a3);     a3 = fdot2(vv.y, w[97+(q4)], a3);\
        a3 = fdot2(vv.z, w[98+(q4)], a3);     a3 = fdot2(vv.w, w[99+(q4)], a3);
        DQ(v0, 0) DQ(v1, 4) DQ(v2, 8) DQ(v3, 12)
        DQ(v4, 16) DQ(v5, 20) DQ(v6, 24) DQ(v7, 28)
#undef DQ
        float4 part; part.x = a0; part.y = a1; part.z = a2; part.w = a3;
        *(float4*)&gates[u & 1][ksl][m][0] = part;
        __syncthreads();                       // the ONLY barrier per step
        // ---- B
        if ((u & 31) == 0 && u && wv < 2) {    // flush h2 over consumed h1
            u32* dst = hbase + (size_t)(u - 32) * 64;
            const u32* sb = och[((u >> 5) & 1) ^ 1];
            const int t0 = tid & 127;
#pragma unroll
            for (int k = 0; k < 4; ++k)
                *(uint4*)(dst + (t0 + k * 128) * 4) =
                    *(const uint4*)(sb + (t0 + k * 128) * 4);
        }
        if ((u & 63) == 32 && u + 32 < S_ && wv < 2) {   // stage next window
            const int nw = (u >> 6) + 1;
            const u32* sw = hbase + (size_t)nw * 4096;
            u32* dw = h1w[nw & 1];
            const int t0 = tid & 127;
#pragma unroll
            for (int k = 0; k < 8; ++k) {
                const int i = t0 + k * 128;
                *(uint4*)&dw[(i >> 4) * 80 + ((i & 15) >> 2) * 20 + (i & 3) * 4] =
                    *(const uint4*)(sw + i * 4);
            }
        }
        if (ksl >= 2) {                        // waves 4-7: activations
            const float4 s0 = *(const float4*)&gates[u & 1][0][unit][0];
            const float4 s1 = *(const float4*)&gates[u & 1][1][unit][0];
            const float4 s2 = *(const float4*)&gates[u & 1][2][unit][0];
            const float4 s3 = *(const float4*)&gates[u & 1][3][unit][0];
            const float ig = sigm((s0.x + s1.x) + (s2.x + s3.x) + bias0);
            const float fg = sigm((s0.y + s1.y) + (s2.y + s3.y) + bias1);
            const float gc = tanh_((s0.z + s1.z) + (s2.z + s3.z) + bias2);
            const float og = sigm((s0.w + s1.w) + (s2.w + s3.w) + bias3);
            c = fg * c + ig * gc;
            const float h = og * tanh_(c);
            const u32 pp = packh2(h, dnb1(h));
            if (!(j & 1)) {
                hb[wv][j >> 1] = pp;
                if (!(wv & 1)) och[(u >> 5) & 1][(u & 31) * 64 + (unit >> 1)] = pp;
            }
            if (u == S_ - 1 && !(wv & 1)) {
                out[HH0 + 32768 + (size_t)b * H_ + unit] = h;
                out[HC0 + 32768 + (size_t)b * H_ + unit] = c;
            }
        }
    }
    __syncthreads();
    {   // final flush: steps [2016, 2048), och buffer 1
        u32* dst = hbase + (size_t)(S_ - 32) * 64;
        *(uint4*)(dst + tid * 4) = *(const uint4*)&och[1][tid * 4];
    }
}

// ===================== heads: parallel over (b,s) ===========================
__global__ __launch_bounds__(256) void k_heads(
    const u32* __restrict__ h2p,
    const float* __restrict__ Wr1, const float* __restrict__ br1,
    const float* __restrict__ Wr2, const float* __restrict__ br2,
    const float* __restrict__ Wv1, const float* __restrict__ bv1,
    const float* __restrict__ Wv2, const float* __restrict__ bv2,
    float* __restrict__ out)
{
    __shared__ u32 wr[64 * 64], wv[64 * 64];
    __shared__ float w2r[64], w2v[64], b1r[64], b1v[64];

    const int tid = threadIdx.x;
    for (int i = tid; i < 4096; i += 256) {
        wr[i] = packh2(Wr1[2 * i], Wr1[2 * i + 1]);
        wv[i] = packh2(Wv1[2 * i], Wv1[2 * i + 1]);
    }
    if (tid < 64) {
        w2r[tid] = Wr2[tid]; w2v[tid] = Wv2[tid];
        b1r[tid] = br1[tid]; b1v[tid] = bv1[tid];
    }
    __syncthreads();

    const size_t bs = (size_t)blockIdx.x * 256 + tid;
    u32 hq[64];
    const u32* src = h2p + bs * 64;
#pragma unroll
    for (int j4 = 0; j4 < 16; ++j4) {
        const uint4 v = *(const uint4*)(src + j4 * 4);
        hq[j4 * 4] = v.x; hq[j4 * 4 + 1] = v.y;
        hq[j4 * 4 + 2] = v.z; hq[j4 * 4 + 3] = v.w;
    }
    float ret = br2[0], vol = bv2[0];
    for (int k = 0; k < 64; ++k) {
        float r = b1r[k], v = b1v[k];
#pragma unroll
        for (int j = 0; j < 64; ++j) r = fdot2(hq[j], wr[k * 64 + j], r);
#pragma unroll
        for (int j = 0; j < 64; ++j) v = fdot2(hq[j], wv[k * 64 + j], v);
        r = r > 0.f ? r : 0.01f * r;
        v = v > 0.f ? v : 0.01f * v;
        ret += r * w2r[k];
        vol += v * w2v[k];
    }
    out[RET0 + bs] = ret;
    out[VOL0 + bs] = softplus_(vol);
}

extern "C" void kernel_launch(void* const* d_in, const int* in_sizes, int n_in,
                              void* d_out, int out_size, void* d_ws, size_t ws_size,
                              hipStream_t stream) {
    (void)in_sizes; (void)n_in; (void)out_size; (void)ws_size;
    const float* x    = (const float*)d_in[0];
    const float* Wih0 = (const float*)d_in[1];
    const float* Whh0 = (const float*)d_in[2];
    const float* bih0 = (const float*)d_in[3];
    const float* bhh0 = (const float*)d_in[4];
    const float* Wih1 = (const float*)d_in[5];
    const float* Whh1 = (const float*)d_in[6];
    const float* bih1 = (const float*)d_in[7];
    const float* bhh1 = (const float*)d_in[8];
    const float* Wr1  = (const float*)d_in[9];
    const float* br1  = (const float*)d_in[10];
    const float* Wr2  = (const float*)d_in[11];
    const float* br2  = (const float*)d_in[12];
    const float* Wv1  = (const float*)d_in[13];
    const float* bv1  = (const float*)d_in[14];
    const float* Wv2  = (const float*)d_in[15];
    const float* bv2  = (const float*)d_in[16];
    u32* hws  = (u32*)d_ws;           // 134 MB: h1 pairs, then h2 in-place
    float* out = (float*)d_out;

    k_l0<<<B_, 512, 0, stream>>>(x, Wih0, Whh0, bih0, bhh0, hws, out);
    k_l1<<<B_, 512, 0, stream>>>(hws, Wih1, Whh1, bih1, bhh1, out);
    k_heads<<<2048, 256, 0, stream>>>(hws, Wr1, br1, Wr2, br2,
                                      Wv1, bv1, Wv2, bv2, out);
}